// Round 18
// baseline (92.339 us; speedup 1.0000x reference)
//
#include <hip/hip_runtime.h>
#include <stdint.h>

typedef unsigned long long u64;
typedef unsigned int u32;

#define BB 4
#define NN 321408
#define K_PRE 1000
#define K_POST 300
#define CAP 4096
#define NW 16                 // 1000 bits -> 16 u64 words
#define SCORE_THR 0.05f
#define IOU_THR 0.5f
#define SB 314                // slice blocks per batch (ceil(NN/1024))
#define CH2 1024              // anchors per slice block
#define NBINS 576             // 16-bit key prefixes span 0xBD4C..0xBF80 (s in [0.05,1.0])
#define BIN0 0xBD4Cu
#define RED 8                 // wide 2-stage reduce (NEVER 4-block serial — R7/R11 lesson)
#define RCH 40

__device__ __forceinline__ float sigm(float x) { return 1.0f / (1.0f + expf(-x)); }

__device__ __forceinline__ u32 mkkey(float mx) {
    float s = sigm(mx);
    return (s >= SCORE_THR) ? (__float_as_uint(s) | 0x80000000u) : 0u;
}

// ---------------- K1: keys + 576-bin LDS hist, stored SUFFIX-cumulative per slice ----------------
__global__ void k_score_hist(const float* __restrict__ cls, u32* __restrict__ key, u32* __restrict__ bh) {
    __shared__ u32 h1[NBINS], h2[NBINS];
    int bb = blockIdx.x, tid = threadIdx.x;       // grid = BB*SB
    int b = bb / SB, c = bb % SB;
    for (int i = tid; i < NBINS; i += 256) h1[i] = 0;
    __syncthreads();
    int a0 = c * CH2 + tid * 4;                   // NN % 4 == 0: full quads only
    if (a0 < NN) {
        const float4* c4 = (const float4*)(cls + ((size_t)b * NN + a0) * 3);
        float4 v0 = c4[0], v1 = c4[1], v2 = c4[2];
        uint4 o;
        o.x = mkkey(fmaxf(v0.x, fmaxf(v0.y, v0.z)));
        o.y = mkkey(fmaxf(v0.w, fmaxf(v1.x, v1.y)));
        o.z = mkkey(fmaxf(v1.z, fmaxf(v1.w, v2.x)));
        o.w = mkkey(fmaxf(v2.y, fmaxf(v2.z, v2.w)));
        *((uint4*)(key + (size_t)b * NN + a0)) = o;
        if (o.x) atomicAdd(&h1[min((o.x >> 16) - BIN0, (u32)(NBINS - 1))], 1u);
        if (o.y) atomicAdd(&h1[min((o.y >> 16) - BIN0, (u32)(NBINS - 1))], 1u);
        if (o.z) atomicAdd(&h1[min((o.z >> 16) - BIN0, (u32)(NBINS - 1))], 1u);
        if (o.w) atomicAdd(&h1[min((o.w >> 16) - BIN0, (u32)(NBINS - 1))], 1u);
    }
    __syncthreads();
    u32* src = h1; u32* dst = h2;
    for (int off = 1; off < NBINS; off <<= 1) {   // 10-pass suffix scan
        for (int i = tid; i < NBINS; i += 256)
            dst[i] = src[i] + ((i + off < NBINS) ? src[i + off] : 0u);
        __syncthreads();
        u32* t = src; src = dst; dst = t;
    }
    for (int i = tid; i < NBINS; i += 256) bh[(size_t)bb * NBINS + i] = src[i];
}

// ---------------- K2: WIDE column-sum of slice suffix-hists -> partials ----------------
__global__ __launch_bounds__(64) void k_red(const u32* __restrict__ bh, u32* __restrict__ part) {
    int blk = blockIdx.x, tid = threadIdx.x;      // grid = BB*RED*9, block = 64
    int b = blk / (RED * 9);
    int r = (blk / 9) % RED;
    int g = blk % 9;
    int f = g * 64 + tid;                          // < 576
    int s0 = r * RCH, s1 = s0 + RCH; if (s1 > SB) s1 = SB;
    const u32* base = bh + (size_t)(b * SB + s0) * NBINS + f;
    u32 acc = 0;
    int n = s1 - s0;
    #pragma unroll 8
    for (int s = 0; s < n; ++s) acc += base[(size_t)s * NBINS];
    part[(size_t)(b * RED + r) * NBINS + f] = acc;
}

// ---------------- K3 (fused scanoff+scatter): per-block threshold + own offset + scatter ----------------
__global__ __launch_bounds__(256) void k_scatterT(const u32* __restrict__ key, const u32* __restrict__ part,
                                                  const u32* __restrict__ bh, u32* __restrict__ cnt,
                                                  u64* __restrict__ cand) {
    __shared__ u32 tot[NBINS];
    __shared__ u32 wtot[4];
    __shared__ u32 sTf;
    int bb = blockIdx.x, tid = threadIdx.x;       // grid = BB*SB
    int b = bb / SB, c = bb % SB;
    int lane = tid & 63, wv = tid >> 6;
    for (int f = tid; f < NBINS; f += 256) {
        u32 x = 0;
        #pragma unroll
        for (int r = 0; r < RED; ++r) x += part[(size_t)(b * RED + r) * NBINS + f];
        tot[f] = x;                                // suffix count >= bin f
    }
    __syncthreads();
    u32 tv = tot[0];
    u32 target = (tv < K_PRE) ? tv : K_PRE;
    if (target == 0) {
        if (c == 0 && tid == 0) cnt[b] = 0;
        return;
    }
    for (int f = tid; f < NBINS; f += 256) {       // tot non-increasing -> unique crossing
        u32 cge = tot[f];
        u32 cnx = (f + 1 < NBINS) ? tot[f + 1] : 0u;
        if (cge >= target && cnx < target) sTf = (u32)f;
    }
    __syncthreads();
    u32 Tf = sTf;
    if (c == 0 && tid == 0) cnt[b] = tot[Tf];
    u32 m = 0;
    if (tid < c) m = bh[(size_t)(b * SB + tid) * NBINS + Tf];
    if (tid + 256 < c) m += bh[(size_t)(b * SB + tid + 256) * NBINS + Tf];
    #pragma unroll
    for (int o = 32; o > 0; o >>= 1) m += __shfl_down(m, o);
    if (lane == 0) wtot[wv] = m;
    __syncthreads();
    u32 boffc = wtot[0] + wtot[1] + wtot[2] + wtot[3];
    __syncthreads();
    u32 T16 = BIN0 + Tf;
    int a0 = c * CH2 + tid * 4;
    uint4 kk = make_uint4(0u, 0u, 0u, 0u);
    if (a0 < NN) kk = *((const uint4*)(key + (size_t)b * NN + a0));
    u32 ks[4] = {kk.x, kk.y, kk.z, kk.w};
    u32 f4[4];
    #pragma unroll
    for (int e = 0; e < 4; ++e) f4[e] = (u32)((ks[e] != 0) && ((ks[e] >> 16) >= T16));
    u32 tc = f4[0] + f4[1] + f4[2] + f4[3];
    u32 x = tc;
    #pragma unroll
    for (int o = 1; o < 64; o <<= 1) {
        u32 y = __shfl_up(x, o);
        if (lane >= o) x += y;
    }
    if (lane == 63) wtot[wv] = x;
    __syncthreads();
    u32 base = 0;
    { u32 w0 = wtot[0], w1 = wtot[1], w2 = wtot[2];
      if (wv > 0) base += w0; if (wv > 1) base += w1; if (wv > 2) base += w2; }
    u32 pos = boffc + base + x - tc;
    u64* cb = cand + (size_t)b * CAP;
    #pragma unroll
    for (int e = 0; e < 4; ++e) {
        if (f4[e]) {
            if (pos < CAP) cb[pos] = ((u64)(~ks[e]) << 32) | (u64)(a0 + e);
            ++pos;
        }
    }
}

// ---------------- K4: rank (dense permutation, keys unique) + decode fused ----------------
__global__ __launch_bounds__(256) void k_rankdec(const u32* __restrict__ cnt, const u64* __restrict__ cand,
                                                 const float* __restrict__ boxp, const float* __restrict__ cls,
                                                 const float* __restrict__ dirp, const float* __restrict__ anch,
                                                 float* __restrict__ tks, u32* __restrict__ meta,
                                                 float* __restrict__ box7, float* __restrict__ cor) {
    __shared__ u64 ck[CAP];                       // 32 KB
    int blk = blockIdx.x, tid = threadIdx.x;      // grid = BB*16
    int b = blk >> 4, rb = blk & 15;
    u32 nc = cnt[b]; if (nc > CAP) nc = CAP;
    int ci = rb * 256 + tid;
    if (rb * 256 >= (int)nc && rb * 256 >= K_PRE) return;
    const u64* cb = cand + (size_t)b * CAP;
    for (int i = tid; i < (int)nc; i += 256) ck[i] = cb[i];
    __syncthreads();

    int rank = -1; u32 idx = 0xFFFFFFFFu;
    if (ci < (int)nc) {
        u64 my = ck[ci];
        u32 r = 0;
        int j = 0;
        int nlim = (int)nc & ~15;
        for (; j < nlim; j += 16) {               // 16 independent LDS broadcast reads in flight
            u64 v0 = ck[j+0], v1 = ck[j+1], v2 = ck[j+2], v3 = ck[j+3];
            u64 v4 = ck[j+4], v5 = ck[j+5], v6 = ck[j+6], v7 = ck[j+7];
            u64 v8 = ck[j+8], v9 = ck[j+9], va = ck[j+10], vb = ck[j+11];
            u64 vc = ck[j+12], vd = ck[j+13], ve = ck[j+14], vf = ck[j+15];
            r += (u32)(v0 < my) + (u32)(v1 < my) + (u32)(v2 < my) + (u32)(v3 < my)
               + (u32)(v4 < my) + (u32)(v5 < my) + (u32)(v6 < my) + (u32)(v7 < my)
               + (u32)(v8 < my) + (u32)(v9 < my) + (u32)(va < my) + (u32)(vb < my)
               + (u32)(vc < my) + (u32)(vd < my) + (u32)(ve < my) + (u32)(vf < my);
        }
        for (; j < (int)nc; ++j) r += (u32)(ck[j] < my);
        if (r < K_PRE) { rank = (int)r; idx = (u32)my; }
    } else if (ci < K_PRE) {
        rank = ci;                                 // invalid-slot filler (disjoint from real ranks)
    }
    if (rank < 0) return;

    float ob[7] = {0,0,0,0,0,0,0};
    float c5[5] = {0,0,0,0,0};
    float sc = 0.f; u32 mt = 0;
    if (idx != 0xFFFFFFFFu) {
        const float* A = anch + (size_t)idx * 7;
        const float* D = boxp + ((size_t)b * NN + idx) * 7;
        float xa=A[0], ya=A[1], za=A[2], wa=A[3], la=A[4], ha=A[5], ra=A[6];
        float xt=D[0], yt=D[1], zt=D[2], wt=D[3], lt=D[4], ht=D[5], rt=D[6];
        za = za + ha * 0.5f;
        float diag = sqrtf(la * la + wa * wa);
        float xg = xt * diag + xa;
        float yg = yt * diag + ya;
        float zg = zt * ha + za;
        float wg = expf(wt) * wa;
        float lg = expf(lt) * la;
        float hg = expf(ht) * ha;
        zg = zg - hg * 0.5f;
        float rg = rt + ra;
        ob[0]=xg; ob[1]=yg; ob[2]=zg; ob[3]=wg; ob[4]=lg; ob[5]=hg; ob[6]=rg;
        float cr = fabsf(cosf(rg)), sr = fabsf(sinf(rg));
        float hx = 0.5f * (wg * cr + lg * sr);
        float hy = 0.5f * (wg * sr + lg * cr);
        float x1 = xg - hx, x2 = xg + hx, y1 = yg - hy, y2 = yg + hy;
        c5[0]=x1; c5[1]=x2; c5[2]=y1; c5[3]=y2; c5[4]=(x2-x1)*(y2-y1);
        const float* cc = cls + ((size_t)b * NN + idx) * 3;
        float p0 = sigm(cc[0]), p1 = sigm(cc[1]), p2 = sigm(cc[2]);
        int lbl = 0; float best = p0;
        if (p1 > best) { best = p1; lbl = 1; }
        if (p2 > best) { best = p2; lbl = 2; }
        sc = best;
        const float* dd = dirp + ((size_t)b * NN + idx) * 2;
        int dl = (dd[1] > dd[0]) ? 1 : 0;
        mt = (u32)lbl | ((u32)dl << 8) | (1u << 16);
    }
    size_t t = (size_t)b * K_PRE + rank;
    tks[t] = sc; meta[t] = mt;
    #pragma unroll
    for (int j = 0; j < 7; ++j) box7[t * 7 + j] = ob[j];
    #pragma unroll
    for (int j = 0; j < 5; ++j) cor[t * 5 + j] = c5[j];
}

// ---------------- K5: TRANSPOSED suppression bitmask (LDS-staged boxes) ----------------
__global__ __launch_bounds__(256) void k_maskT(const float* __restrict__ cor, u64* __restrict__ maskT) {
    __shared__ float s4[(K_PRE + 16) * 4];        // index i+(i>>6) breaks bank conflicts
    __shared__ float sA[K_PRE + 16];
    int blk = blockIdx.x;                         // grid = BB * 63
    int b = blk / 63, jb = blk % 63;
    int tid = threadIdx.x;
    const float4* C4 = (const float4*)(cor + (size_t)b * K_PRE * 5);
    for (int q = tid; q < (K_PRE * 5) / 4; q += 256) {
        float4 v = C4[q];
        int t0 = q * 4;
        #pragma unroll
        for (int e = 0; e < 4; ++e) {
            int t = t0 + e;
            int i = t / 5, k = t - i * 5;
            float val = (e == 0) ? v.x : (e == 1) ? v.y : (e == 2) ? v.z : v.w;
            int ip = i + (i >> 6);
            if (k < 4) s4[ip * 4 + k] = val; else sA[ip] = val;
        }
    }
    __syncthreads();
    int w = tid & 15, jl = tid >> 4;
    int j = jb * 16 + jl;
    if (j >= K_PRE) return;
    int jp = j + (j >> 6);
    float x1 = s4[jp*4+0], x2 = s4[jp*4+1], y1 = s4[jp*4+2], y2 = s4[jp*4+3], ar = sA[jp];
    u64 m = 0;
    int i0 = w * 64;
    if (i0 < j) {
        int iend = j - i0; if (iend > 64) iend = 64;
        for (int ii = 0; ii < iend; ++ii) {
            int i = i0 + ii;
            int ip = i + (i >> 6);
            float4 bx = *(const float4*)&s4[ip * 4];
            float ai = sA[ip];
            float ix = fminf(x2, bx.y) - fmaxf(x1, bx.x); ix = fmaxf(ix, 0.f);
            float iy = fminf(y2, bx.w) - fmaxf(y1, bx.z); iy = fmaxf(iy, 0.f);
            float inter = ix * iy;
            float uni = ai + ar - inter;              // fp-add commutative == ref order
            float iou = (uni > 0.f) ? inter / fmaxf(uni, 1e-12f) : 0.f;
            if (iou > IOU_THR) m |= (1ull << ii);
        }
    }
    maskT[((size_t)b * K_PRE + j) * NW + w] = m;
}

// in-wave 64x64 bit-matrix transpose: lane j holds row j (bit i) -> lane l holds col l (bit j)
__device__ __forceinline__ u64 bit_transpose64(u64 x, int lane) {
    #pragma unroll
    for (int k = 0; k < 6; ++k) {
        const int s = 32 >> k;
        const u64 Mhi = (k == 0) ? 0xFFFFFFFF00000000ull :
                        (k == 1) ? 0xFFFF0000FFFF0000ull :
                        (k == 2) ? 0xFF00FF00FF00FF00ull :
                        (k == 3) ? 0xF0F0F0F0F0F0F0F0ull :
                        (k == 4) ? 0xCCCCCCCCCCCCCCCCull : 0xAAAAAAAAAAAAAAAAull;
        u64 y = (u64)__shfl_xor((long long)x, s);
        if ((lane & s) == 0) x = (x & ~Mhi) | ((y << s) & Mhi);
        else                 x = (x & Mhi) | ((y >> s) & ~Mhi);
    }
    return x;
}

// ---------------- K6: greedy NMS — ballot-free inner loop via column masks (readlane) ----------------
__global__ __launch_bounds__(256) void k_nms_out(const u32* __restrict__ meta, const float* __restrict__ box7,
                                                 const float* __restrict__ tks, const u64* __restrict__ maskT,
                                                 float* __restrict__ out) {
    int b = blockIdx.x; int tid = threadIdx.x;
    int lane = tid & 63, wvi = tid >> 6;
    __shared__ u64 mrow[64 * 17];                 // transpose buffer, +1-row pad
    __shared__ u64 vb_s[16];                      // validity bitmap (1000 bits)
    __shared__ u64 km_s[16];                      // kept-bits per chunk (wave-0 private)
    __shared__ int sel_s[K_POST];
    __shared__ int cnt_s;
    const u32* M = meta + b * K_PRE;
    const u64* Mk = maskT + (size_t)b * K_PRE * NW;

    // validity bitmap: 4 coalesced rounds of ballot
    for (int base = 0; base < K_PRE; base += 256) {
        int slot = base + tid;
        bool v = (slot < K_PRE) && ((M[slot] >> 16) & 1u);
        u64 word = __ballot(v);
        if (lane == 0) vb_s[(base >> 6) + wvi] = word;
    }
    if (tid < 16) km_s[tid] = 0ull;
    __syncthreads();

    if (tid < 64) {                               // wave 0 runs the whole greedy chain
        int wsel = lane & 15, rq = lane >> 4;     // word select / row quarter
        int cnt = 0; bool done = false;
        for (int c = 0; c < 16 && !done; ++c) {
            // coalesced load of chunk c (64 rows x 16 u64): instr k covers 4 rows = 512 B contiguous
            u64 v[16];
            #pragma unroll
            for (int k = 0; k < 16; ++k) {
                int row = c * 64 + k * 4 + rq;
                int rc = (row < K_PRE) ? row : (K_PRE - 1);   // clamped rows are invalid anyway
                v[k] = Mk[(size_t)rc * NW + wsel];
            }
            #pragma unroll
            for (int k = 0; k < 16; ++k)
                mrow[(k * 4 + rq) * 17 + wsel] = v[k];        // transpose via LDS (same wave)
            u64 cw = 0;
            u64 supacc = 0;
            #pragma unroll
            for (int w = 0; w < 16; ++w) {
                u64 mv = mrow[lane * 17 + w];
                supacc |= (mv & km_s[w]);                      // km_s[w]=0 for w>=c
                if (w == c) cw = mv;
            }
            // per-lane column mask: bit j = "my box (lane) suppresses box j of this chunk"
            u64 colmask = bit_transpose64(cw, lane);
            int j = c * 64 + lane;
            bool jvalid = (j < K_PRE) && (((vb_s[c] >> lane) & 1ull) != 0ull);
            u64 active = __ballot(jvalid && (supacc == 0ull));
            u64 kmc = 0;
            while (active) {
                int i = __ffsll((unsigned long long)active) - 1;
                if (lane == 0) sel_s[cnt] = c * 64 + i;        // off critical path
                ++cnt;
                if (cnt >= K_POST) { done = true; break; }
                kmc |= (1ull << i);
                u32 clo = (u32)__builtin_amdgcn_readlane((int)(u32)(colmask & 0xFFFFFFFFull), i);
                u32 chi = (u32)__builtin_amdgcn_readlane((int)(u32)(colmask >> 32), i);
                u64 coli = ((u64)chi << 32) | (u64)clo;        // == old ballot(cw bit i)
                active &= ~coli;
                active &= ~(1ull << i);
            }
            km_s[c] = kmc;                         // wave-0 write/read only; no barrier needed
        }
        if (lane == 0) cnt_s = cnt;
    }
    __syncthreads();

    int kept = cnt_s;
    const float* BX = box7 + (size_t)b * K_PRE * 7;
    const float* SS = tks + b * K_PRE;
    for (int p = tid; p < K_POST; p += 256) {
        float ob[7] = {0,0,0,0,0,0,0};
        float sc = 0.f, lb = 0.f, vd = 0.f;
        if (p < kept) {
            int i = sel_s[p];
            float xg = BX[i*7+0], yg = BX[i*7+1], zg = BX[i*7+2];
            bool in_range = (xg >= 0.0f) && (xg <= 69.12f) &&
                            (yg >= -39.68f) && (yg <= 39.68f) &&
                            (zg >= -5.0f) && (zg <= 5.0f);
            if (in_range) {
                u32 mt = M[i];
                int dl = (mt >> 8) & 0xFF;
                float r = BX[i*7+6];
                bool opp = ((r > 0.0f) != (dl == 1));
                float rf = r + (opp ? 3.14159274f : 0.0f);
                ob[0]=xg; ob[1]=yg; ob[2]=zg; ob[3]=BX[i*7+3]; ob[4]=BX[i*7+4]; ob[5]=BX[i*7+5]; ob[6]=rf;
                sc = SS[i]; lb = (float)(mt & 0xFF); vd = 1.0f;
            }
        }
        size_t ro = (size_t)(b * K_POST + p);
        #pragma unroll
        for (int j = 0; j < 7; ++j) out[ro * 7 + j] = ob[j];
        out[(size_t)BB * K_POST * 7 + ro] = lb;   // labels
        out[(size_t)BB * K_POST * 8 + ro] = sc;   // scores
        out[(size_t)BB * K_POST * 9 + ro] = vd;   // valid
    }
}

extern "C" void kernel_launch(void* const* d_in, const int* in_sizes, int n_in,
                              void* d_out, int out_size, void* d_ws, size_t ws_size,
                              hipStream_t stream) {
    const float* boxp = (const float*)d_in[0];
    const float* cls  = (const float*)d_in[1];
    const float* dirp = (const float*)d_in[2];
    const float* anch = (const float*)d_in[3];
    float* out = (float*)d_out;

    char* p = (char*)d_ws;
    u32* key  = (u32*)p; p += (size_t)BB * NN * 4;
    u32* bh   = (u32*)p; p += (size_t)BB * SB * NBINS * 4;   // suffix-hist slices
    u32* part = (u32*)p; p += (size_t)BB * RED * NBINS * 4;  // column-sum partials
    u32* cnt  = (u32*)p; p += 256;
    u64* cand = (u64*)p; p += (size_t)BB * CAP * 8;
    float* tks = (float*)p; p += (size_t)BB * K_PRE * 4;
    u32* meta = (u32*)p; p += (size_t)BB * K_PRE * 4;
    float* box7 = (float*)p; p += (size_t)BB * K_PRE * 7 * 4;
    float* cor  = (float*)p; p += (size_t)BB * K_PRE * 5 * 4;
    u64* maskT = (u64*)p; p += (size_t)BB * K_PRE * NW * 8;

    k_score_hist<<<BB * SB, 256, 0, stream>>>(cls, key, bh);
    k_red<<<BB * RED * 9, 64, 0, stream>>>(bh, part);
    k_scatterT<<<BB * SB, 256, 0, stream>>>(key, part, bh, cnt, cand);
    k_rankdec<<<BB * 16, 256, 0, stream>>>(cnt, cand, boxp, cls, dirp, anch, tks, meta, box7, cor);
    k_maskT<<<BB * 63, 256, 0, stream>>>(cor, maskT);
    k_nms_out<<<BB, 256, 0, stream>>>(meta, box7, tks, maskT, out);
}

// Round 19
// 87.364 us; speedup vs baseline: 1.0569x; 1.0569x over previous
//
#include <hip/hip_runtime.h>
#include <stdint.h>

typedef unsigned long long u64;
typedef unsigned int u32;

#define BB 4
#define NN 321408
#define K_PRE 1000
#define K_POST 300
#define CAP 4096
#define NW 16                 // 1000 bits -> 16 u64 words
#define SCORE_THR 0.05f
#define IOU_THR 0.5f
#define SB 314                // slice blocks per batch (ceil(NN/1024))
#define CH2 1024              // anchors per slice block
#define NBINS 576             // 16-bit key prefixes span 0xBD4C..0xBF80 (s in [0.05,1.0])
#define BIN0 0xBD4Cu
#define RED 8                 // wide 2-stage reduce (NEVER 4-block serial — R7/R11 lesson)
#define RCH 40

__device__ __forceinline__ float sigm(float x) { return 1.0f / (1.0f + expf(-x)); }

__device__ __forceinline__ u32 mkkey(float mx) {
    float s = sigm(mx);
    return (s >= SCORE_THR) ? (__float_as_uint(s) | 0x80000000u) : 0u;
}

// ---------------- K1: keys + 576-bin LDS hist, stored SUFFIX-cumulative per slice ----------------
__global__ void k_score_hist(const float* __restrict__ cls, u32* __restrict__ key, u32* __restrict__ bh) {
    __shared__ u32 h1[NBINS], h2[NBINS];
    int bb = blockIdx.x, tid = threadIdx.x;       // grid = BB*SB
    int b = bb / SB, c = bb % SB;
    for (int i = tid; i < NBINS; i += 256) h1[i] = 0;
    __syncthreads();
    int a0 = c * CH2 + tid * 4;                   // NN % 4 == 0: full quads only
    if (a0 < NN) {
        const float4* c4 = (const float4*)(cls + ((size_t)b * NN + a0) * 3);
        float4 v0 = c4[0], v1 = c4[1], v2 = c4[2];
        uint4 o;
        o.x = mkkey(fmaxf(v0.x, fmaxf(v0.y, v0.z)));
        o.y = mkkey(fmaxf(v0.w, fmaxf(v1.x, v1.y)));
        o.z = mkkey(fmaxf(v1.z, fmaxf(v1.w, v2.x)));
        o.w = mkkey(fmaxf(v2.y, fmaxf(v2.z, v2.w)));
        *((uint4*)(key + (size_t)b * NN + a0)) = o;
        if (o.x) atomicAdd(&h1[min((o.x >> 16) - BIN0, (u32)(NBINS - 1))], 1u);
        if (o.y) atomicAdd(&h1[min((o.y >> 16) - BIN0, (u32)(NBINS - 1))], 1u);
        if (o.z) atomicAdd(&h1[min((o.z >> 16) - BIN0, (u32)(NBINS - 1))], 1u);
        if (o.w) atomicAdd(&h1[min((o.w >> 16) - BIN0, (u32)(NBINS - 1))], 1u);
    }
    __syncthreads();
    u32* src = h1; u32* dst = h2;
    for (int off = 1; off < NBINS; off <<= 1) {   // 10-pass suffix scan
        for (int i = tid; i < NBINS; i += 256)
            dst[i] = src[i] + ((i + off < NBINS) ? src[i + off] : 0u);
        __syncthreads();
        u32* t = src; src = dst; dst = t;
    }
    for (int i = tid; i < NBINS; i += 256) bh[(size_t)bb * NBINS + i] = src[i];
}

// ---------------- K2: WIDE column-sum of slice suffix-hists -> partials ----------------
__global__ __launch_bounds__(64) void k_red(const u32* __restrict__ bh, u32* __restrict__ part) {
    int blk = blockIdx.x, tid = threadIdx.x;      // grid = BB*RED*9, block = 64
    int b = blk / (RED * 9);
    int r = (blk / 9) % RED;
    int g = blk % 9;
    int f = g * 64 + tid;                          // < 576
    int s0 = r * RCH, s1 = s0 + RCH; if (s1 > SB) s1 = SB;
    const u32* base = bh + (size_t)(b * SB + s0) * NBINS + f;
    u32 acc = 0;
    int n = s1 - s0;
    #pragma unroll 8
    for (int s = 0; s < n; ++s) acc += base[(size_t)s * NBINS];
    part[(size_t)(b * RED + r) * NBINS + f] = acc;
}

// ---------------- K3 (fused scanoff+scatter): per-block threshold + own offset + scatter ----------------
__global__ __launch_bounds__(256) void k_scatterT(const u32* __restrict__ key, const u32* __restrict__ part,
                                                  const u32* __restrict__ bh, u32* __restrict__ cnt,
                                                  u64* __restrict__ cand) {
    __shared__ u32 tot[NBINS];
    __shared__ u32 wtot[4];
    __shared__ u32 sTf;
    int bb = blockIdx.x, tid = threadIdx.x;       // grid = BB*SB
    int b = bb / SB, c = bb % SB;
    int lane = tid & 63, wv = tid >> 6;
    for (int f = tid; f < NBINS; f += 256) {
        u32 x = 0;
        #pragma unroll
        for (int r = 0; r < RED; ++r) x += part[(size_t)(b * RED + r) * NBINS + f];
        tot[f] = x;                                // suffix count >= bin f
    }
    __syncthreads();
    u32 tv = tot[0];
    u32 target = (tv < K_PRE) ? tv : K_PRE;
    if (target == 0) {
        if (c == 0 && tid == 0) cnt[b] = 0;
        return;
    }
    for (int f = tid; f < NBINS; f += 256) {       // tot non-increasing -> unique crossing
        u32 cge = tot[f];
        u32 cnx = (f + 1 < NBINS) ? tot[f + 1] : 0u;
        if (cge >= target && cnx < target) sTf = (u32)f;
    }
    __syncthreads();
    u32 Tf = sTf;
    if (c == 0 && tid == 0) cnt[b] = tot[Tf];
    u32 m = 0;
    if (tid < c) m = bh[(size_t)(b * SB + tid) * NBINS + Tf];
    if (tid + 256 < c) m += bh[(size_t)(b * SB + tid + 256) * NBINS + Tf];
    #pragma unroll
    for (int o = 32; o > 0; o >>= 1) m += __shfl_down(m, o);
    if (lane == 0) wtot[wv] = m;
    __syncthreads();
    u32 boffc = wtot[0] + wtot[1] + wtot[2] + wtot[3];
    __syncthreads();
    u32 T16 = BIN0 + Tf;
    int a0 = c * CH2 + tid * 4;
    uint4 kk = make_uint4(0u, 0u, 0u, 0u);
    if (a0 < NN) kk = *((const uint4*)(key + (size_t)b * NN + a0));
    u32 ks[4] = {kk.x, kk.y, kk.z, kk.w};
    u32 f4[4];
    #pragma unroll
    for (int e = 0; e < 4; ++e) f4[e] = (u32)((ks[e] != 0) && ((ks[e] >> 16) >= T16));
    u32 tc = f4[0] + f4[1] + f4[2] + f4[3];
    u32 x = tc;
    #pragma unroll
    for (int o = 1; o < 64; o <<= 1) {
        u32 y = __shfl_up(x, o);
        if (lane >= o) x += y;
    }
    if (lane == 63) wtot[wv] = x;
    __syncthreads();
    u32 base = 0;
    { u32 w0 = wtot[0], w1 = wtot[1], w2 = wtot[2];
      if (wv > 0) base += w0; if (wv > 1) base += w1; if (wv > 2) base += w2; }
    u32 pos = boffc + base + x - tc;
    u64* cb = cand + (size_t)b * CAP;
    #pragma unroll
    for (int e = 0; e < 4; ++e) {
        if (f4[e]) {
            if (pos < CAP) cb[pos] = ((u64)(~ks[e]) << 32) | (u64)(a0 + e);
            ++pos;
        }
    }
}

// ---------------- K4: rank (dense permutation, keys unique) + decode fused ----------------
__global__ __launch_bounds__(256) void k_rankdec(const u32* __restrict__ cnt, const u64* __restrict__ cand,
                                                 const float* __restrict__ boxp, const float* __restrict__ cls,
                                                 const float* __restrict__ dirp, const float* __restrict__ anch,
                                                 float* __restrict__ tks, u32* __restrict__ meta,
                                                 float* __restrict__ box7, float* __restrict__ cor) {
    __shared__ u64 ck[CAP];                       // 32 KB
    int blk = blockIdx.x, tid = threadIdx.x;      // grid = BB*16
    int b = blk >> 4, rb = blk & 15;
    u32 nc = cnt[b]; if (nc > CAP) nc = CAP;
    int ci = rb * 256 + tid;
    if (rb * 256 >= (int)nc && rb * 256 >= K_PRE) return;
    const u64* cb = cand + (size_t)b * CAP;
    for (int i = tid; i < (int)nc; i += 256) ck[i] = cb[i];
    __syncthreads();

    int rank = -1; u32 idx = 0xFFFFFFFFu;
    if (ci < (int)nc) {
        u64 my = ck[ci];
        u32 r = 0;
        int j = 0;
        int nlim = (int)nc & ~15;
        for (; j < nlim; j += 16) {               // 16 independent LDS broadcast reads in flight
            u64 v0 = ck[j+0], v1 = ck[j+1], v2 = ck[j+2], v3 = ck[j+3];
            u64 v4 = ck[j+4], v5 = ck[j+5], v6 = ck[j+6], v7 = ck[j+7];
            u64 v8 = ck[j+8], v9 = ck[j+9], va = ck[j+10], vb = ck[j+11];
            u64 vc = ck[j+12], vd = ck[j+13], ve = ck[j+14], vf = ck[j+15];
            r += (u32)(v0 < my) + (u32)(v1 < my) + (u32)(v2 < my) + (u32)(v3 < my)
               + (u32)(v4 < my) + (u32)(v5 < my) + (u32)(v6 < my) + (u32)(v7 < my)
               + (u32)(v8 < my) + (u32)(v9 < my) + (u32)(va < my) + (u32)(vb < my)
               + (u32)(vc < my) + (u32)(vd < my) + (u32)(ve < my) + (u32)(vf < my);
        }
        for (; j < (int)nc; ++j) r += (u32)(ck[j] < my);
        if (r < K_PRE) { rank = (int)r; idx = (u32)my; }
    } else if (ci < K_PRE) {
        rank = ci;                                 // invalid-slot filler (disjoint from real ranks)
    }
    if (rank < 0) return;

    float ob[7] = {0,0,0,0,0,0,0};
    float c5[5] = {0,0,0,0,0};
    float sc = 0.f; u32 mt = 0;
    if (idx != 0xFFFFFFFFu) {
        const float* A = anch + (size_t)idx * 7;
        const float* D = boxp + ((size_t)b * NN + idx) * 7;
        float xa=A[0], ya=A[1], za=A[2], wa=A[3], la=A[4], ha=A[5], ra=A[6];
        float xt=D[0], yt=D[1], zt=D[2], wt=D[3], lt=D[4], ht=D[5], rt=D[6];
        za = za + ha * 0.5f;
        float diag = sqrtf(la * la + wa * wa);
        float xg = xt * diag + xa;
        float yg = yt * diag + ya;
        float zg = zt * ha + za;
        float wg = expf(wt) * wa;
        float lg = expf(lt) * la;
        float hg = expf(ht) * ha;
        zg = zg - hg * 0.5f;
        float rg = rt + ra;
        ob[0]=xg; ob[1]=yg; ob[2]=zg; ob[3]=wg; ob[4]=lg; ob[5]=hg; ob[6]=rg;
        float cr = fabsf(cosf(rg)), sr = fabsf(sinf(rg));
        float hx = 0.5f * (wg * cr + lg * sr);
        float hy = 0.5f * (wg * sr + lg * cr);
        float x1 = xg - hx, x2 = xg + hx, y1 = yg - hy, y2 = yg + hy;
        c5[0]=x1; c5[1]=x2; c5[2]=y1; c5[3]=y2; c5[4]=(x2-x1)*(y2-y1);
        const float* cc = cls + ((size_t)b * NN + idx) * 3;
        float p0 = sigm(cc[0]), p1 = sigm(cc[1]), p2 = sigm(cc[2]);
        int lbl = 0; float best = p0;
        if (p1 > best) { best = p1; lbl = 1; }
        if (p2 > best) { best = p2; lbl = 2; }
        sc = best;
        const float* dd = dirp + ((size_t)b * NN + idx) * 2;
        int dl = (dd[1] > dd[0]) ? 1 : 0;
        mt = (u32)lbl | ((u32)dl << 8) | (1u << 16);
    }
    size_t t = (size_t)b * K_PRE + rank;
    tks[t] = sc; meta[t] = mt;
    #pragma unroll
    for (int j = 0; j < 7; ++j) box7[t * 7 + j] = ob[j];
    #pragma unroll
    for (int j = 0; j < 5; ++j) cor[t * 5 + j] = c5[j];
}

// ---------------- K5: TRANSPOSED suppression bitmask (LDS-staged boxes) ----------------
__global__ __launch_bounds__(256) void k_maskT(const float* __restrict__ cor, u64* __restrict__ maskT) {
    __shared__ float s4[(K_PRE + 16) * 4];        // index i+(i>>6) breaks bank conflicts
    __shared__ float sA[K_PRE + 16];
    int blk = blockIdx.x;                         // grid = BB * 63
    int b = blk / 63, jb = blk % 63;
    int tid = threadIdx.x;
    const float4* C4 = (const float4*)(cor + (size_t)b * K_PRE * 5);
    for (int q = tid; q < (K_PRE * 5) / 4; q += 256) {
        float4 v = C4[q];
        int t0 = q * 4;
        #pragma unroll
        for (int e = 0; e < 4; ++e) {
            int t = t0 + e;
            int i = t / 5, k = t - i * 5;
            float val = (e == 0) ? v.x : (e == 1) ? v.y : (e == 2) ? v.z : v.w;
            int ip = i + (i >> 6);
            if (k < 4) s4[ip * 4 + k] = val; else sA[ip] = val;
        }
    }
    __syncthreads();
    int w = tid & 15, jl = tid >> 4;
    int j = jb * 16 + jl;
    if (j >= K_PRE) return;
    int jp = j + (j >> 6);
    float x1 = s4[jp*4+0], x2 = s4[jp*4+1], y1 = s4[jp*4+2], y2 = s4[jp*4+3], ar = sA[jp];
    u64 m = 0;
    int i0 = w * 64;
    if (i0 < j) {
        int iend = j - i0; if (iend > 64) iend = 64;
        for (int ii = 0; ii < iend; ++ii) {
            int i = i0 + ii;
            int ip = i + (i >> 6);
            float4 bx = *(const float4*)&s4[ip * 4];
            float ai = sA[ip];
            float ix = fminf(x2, bx.y) - fmaxf(x1, bx.x); ix = fmaxf(ix, 0.f);
            float iy = fminf(y2, bx.w) - fmaxf(y1, bx.z); iy = fmaxf(iy, 0.f);
            float inter = ix * iy;
            float uni = ai + ar - inter;              // fp-add commutative == ref order
            float iou = (uni > 0.f) ? inter / fmaxf(uni, 1e-12f) : 0.f;
            if (iou > IOU_THR) m |= (1ull << ii);
        }
    }
    maskT[((size_t)b * K_PRE + j) * NW + w] = m;
}

// ---------------- K6: greedy NMS — 4-chunk batched loads (deep MLP) + R17 ballot chain ----------------
#define LOADCHUNK(VARR, CIDX)                                                          \
    _Pragma("unroll")                                                                  \
    for (int k = 0; k < 16; ++k) {                                                     \
        int row_ = (CIDX) * 64 + k * 4 + rq;                                           \
        int rc_ = (row_ < K_PRE) ? row_ : (K_PRE - 1);                                 \
        VARR[k] = Mk[(size_t)rc_ * NW + wsel];                                         \
    }

__global__ __launch_bounds__(256) void k_nms_out(const u32* __restrict__ meta, const float* __restrict__ box7,
                                                 const float* __restrict__ tks, const u64* __restrict__ maskT,
                                                 float* __restrict__ out) {
    int b = blockIdx.x; int tid = threadIdx.x;
    int lane = tid & 63, wvi = tid >> 6;
    __shared__ u64 mrow[64 * 17];                 // transpose buffer, +1-row pad
    __shared__ u64 vb_s[16];                      // validity bitmap (1000 bits)
    __shared__ u64 km_s[16];                      // kept-bits per chunk (wave-0 private)
    __shared__ int sel_s[K_POST];
    __shared__ int cnt_s;
    const u32* M = meta + b * K_PRE;
    const u64* Mk = maskT + (size_t)b * K_PRE * NW;

    // validity bitmap: 4 coalesced rounds of ballot
    for (int base = 0; base < K_PRE; base += 256) {
        int slot = base + tid;
        bool v = (slot < K_PRE) && ((M[slot] >> 16) & 1u);
        u64 word = __ballot(v);
        if (lane == 0) vb_s[(base >> 6) + wvi] = word;
    }
    if (tid < 16) km_s[tid] = 0ull;
    __syncthreads();

    if (tid < 64) {                               // wave 0 runs the whole greedy chain
        int wsel = lane & 15, rq = lane >> 4;     // word select / row quarter
        int cnt = 0; bool done = false;
        u64 va[16], vb[16], vc[16], vd[16];
        for (int g = 0; g < 4 && !done; ++g) {
            int cbase = g * 4;
            // issue all 4 chunks' loads back-to-back: 64 load instrs in flight (counted-vmcnt)
            LOADCHUNK(va, cbase + 0)
            LOADCHUNK(vb, cbase + 1)
            LOADCHUNK(vc, cbase + 2)
            LOADCHUNK(vd, cbase + 3)
            #pragma unroll
            for (int cc = 0; cc < 4; ++cc) {
                int c = cbase + cc;
                const u64* vp = (cc == 0) ? va : (cc == 1) ? vb : (cc == 2) ? vc : vd;
                #pragma unroll
                for (int k = 0; k < 16; ++k)
                    mrow[(k * 4 + rq) * 17 + wsel] = vp[k];    // transpose via LDS (same wave)
                u64 cw = 0;
                u64 supacc = 0;
                #pragma unroll
                for (int w = 0; w < 16; ++w) {
                    u64 mv = mrow[lane * 17 + w];
                    supacc |= (mv & km_s[w]);                   // km_s[w]=0 for w>=c
                    if (w == c) cw = mv;
                }
                int j = c * 64 + lane;
                bool jvalid = (j < K_PRE) && (((vb_s[c] >> lane) & 1ull) != 0ull);
                u64 active = __ballot(jvalid && (supacc == 0ull));
                u64 kmc = 0;
                while (active) {
                    int i = __ffsll((unsigned long long)active) - 1;
                    if (lane == 0) sel_s[cnt] = c * 64 + i;
                    ++cnt;
                    if (cnt >= K_POST) { done = true; break; }
                    kmc |= (1ull << i);
                    u64 supb = __ballot(((cw >> i) & 1ull) != 0ull);
                    active &= ~supb;
                    active &= ~(1ull << i);
                }
                km_s[c] = kmc;                     // wave-0 write/read only; no barrier needed
                if (done) break;
            }
        }
        if (lane == 0) cnt_s = cnt;
    }
    __syncthreads();

    int kept = cnt_s;
    const float* BX = box7 + (size_t)b * K_PRE * 7;
    const float* SS = tks + b * K_PRE;
    for (int p = tid; p < K_POST; p += 256) {
        float ob[7] = {0,0,0,0,0,0,0};
        float sc = 0.f, lb = 0.f, vd2 = 0.f;
        if (p < kept) {
            int i = sel_s[p];
            float xg = BX[i*7+0], yg = BX[i*7+1], zg = BX[i*7+2];
            bool in_range = (xg >= 0.0f) && (xg <= 69.12f) &&
                            (yg >= -39.68f) && (yg <= 39.68f) &&
                            (zg >= -5.0f) && (zg <= 5.0f);
            if (in_range) {
                u32 mt = M[i];
                int dl = (mt >> 8) & 0xFF;
                float r = BX[i*7+6];
                bool opp = ((r > 0.0f) != (dl == 1));
                float rf = r + (opp ? 3.14159274f : 0.0f);
                ob[0]=xg; ob[1]=yg; ob[2]=zg; ob[3]=BX[i*7+3]; ob[4]=BX[i*7+4]; ob[5]=BX[i*7+5]; ob[6]=rf;
                sc = SS[i]; lb = (float)(mt & 0xFF); vd2 = 1.0f;
            }
        }
        size_t ro = (size_t)(b * K_POST + p);
        #pragma unroll
        for (int j = 0; j < 7; ++j) out[ro * 7 + j] = ob[j];
        out[(size_t)BB * K_POST * 7 + ro] = lb;   // labels
        out[(size_t)BB * K_POST * 8 + ro] = sc;   // scores
        out[(size_t)BB * K_POST * 9 + ro] = vd2;  // valid
    }
}

extern "C" void kernel_launch(void* const* d_in, const int* in_sizes, int n_in,
                              void* d_out, int out_size, void* d_ws, size_t ws_size,
                              hipStream_t stream) {
    const float* boxp = (const float*)d_in[0];
    const float* cls  = (const float*)d_in[1];
    const float* dirp = (const float*)d_in[2];
    const float* anch = (const float*)d_in[3];
    float* out = (float*)d_out;

    char* p = (char*)d_ws;
    u32* key  = (u32*)p; p += (size_t)BB * NN * 4;
    u32* bh   = (u32*)p; p += (size_t)BB * SB * NBINS * 4;   // suffix-hist slices
    u32* part = (u32*)p; p += (size_t)BB * RED * NBINS * 4;  // column-sum partials
    u32* cnt  = (u32*)p; p += 256;
    u64* cand = (u64*)p; p += (size_t)BB * CAP * 8;
    float* tks = (float*)p; p += (size_t)BB * K_PRE * 4;
    u32* meta = (u32*)p; p += (size_t)BB * K_PRE * 4;
    float* box7 = (float*)p; p += (size_t)BB * K_PRE * 7 * 4;
    float* cor  = (float*)p; p += (size_t)BB * K_PRE * 5 * 4;
    u64* maskT = (u64*)p; p += (size_t)BB * K_PRE * NW * 8;

    k_score_hist<<<BB * SB, 256, 0, stream>>>(cls, key, bh);
    k_red<<<BB * RED * 9, 64, 0, stream>>>(bh, part);
    k_scatterT<<<BB * SB, 256, 0, stream>>>(key, part, bh, cnt, cand);
    k_rankdec<<<BB * 16, 256, 0, stream>>>(cnt, cand, boxp, cls, dirp, anch, tks, meta, box7, cor);
    k_maskT<<<BB * 63, 256, 0, stream>>>(cor, maskT);
    k_nms_out<<<BB, 256, 0, stream>>>(meta, box7, tks, maskT, out);
}

// Round 20
// 75.745 us; speedup vs baseline: 1.2191x; 1.1534x over previous
//
#include <hip/hip_runtime.h>
#include <stdint.h>

typedef unsigned long long u64;
typedef unsigned int u32;

#define BB 4
#define NN 321408
#define K_PRE 1000
#define K_POST 300
#define CAP 4096
#define NW 16                 // 1000 bits -> 16 u64 words
#define SCORE_THR 0.05f
#define IOU_THR 0.5f
#define SB 314                // slice blocks per batch (ceil(NN/1024))
#define CH2 1024              // anchors per slice block
#define NBINS 576             // 16-bit key prefixes span 0xBD4C..0xBF80 (s in [0.05,1.0])
#define BIN0 0xBD4Cu
#define RED 8                 // wide 2-stage reduce (NEVER 4-block serial — R7/R11 lesson)
#define RCH 40

__device__ __forceinline__ float sigm(float x) { return 1.0f / (1.0f + expf(-x)); }

__device__ __forceinline__ u32 mkkey(float mx) {
    float s = sigm(mx);
    return (s >= SCORE_THR) ? (__float_as_uint(s) | 0x80000000u) : 0u;
}

// ---------------- K1: keys + 576-bin LDS hist, stored SUFFIX-cumulative per slice ----------------
__global__ void k_score_hist(const float* __restrict__ cls, u32* __restrict__ key, u32* __restrict__ bh) {
    __shared__ u32 h1[NBINS], h2[NBINS];
    int bb = blockIdx.x, tid = threadIdx.x;       // grid = BB*SB
    int b = bb / SB, c = bb % SB;
    for (int i = tid; i < NBINS; i += 256) h1[i] = 0;
    __syncthreads();
    int a0 = c * CH2 + tid * 4;                   // NN % 4 == 0: full quads only
    if (a0 < NN) {
        const float4* c4 = (const float4*)(cls + ((size_t)b * NN + a0) * 3);
        float4 v0 = c4[0], v1 = c4[1], v2 = c4[2];
        uint4 o;
        o.x = mkkey(fmaxf(v0.x, fmaxf(v0.y, v0.z)));
        o.y = mkkey(fmaxf(v0.w, fmaxf(v1.x, v1.y)));
        o.z = mkkey(fmaxf(v1.z, fmaxf(v1.w, v2.x)));
        o.w = mkkey(fmaxf(v2.y, fmaxf(v2.z, v2.w)));
        *((uint4*)(key + (size_t)b * NN + a0)) = o;
        if (o.x) atomicAdd(&h1[min((o.x >> 16) - BIN0, (u32)(NBINS - 1))], 1u);
        if (o.y) atomicAdd(&h1[min((o.y >> 16) - BIN0, (u32)(NBINS - 1))], 1u);
        if (o.z) atomicAdd(&h1[min((o.z >> 16) - BIN0, (u32)(NBINS - 1))], 1u);
        if (o.w) atomicAdd(&h1[min((o.w >> 16) - BIN0, (u32)(NBINS - 1))], 1u);
    }
    __syncthreads();
    u32* src = h1; u32* dst = h2;
    for (int off = 1; off < NBINS; off <<= 1) {   // 10-pass suffix scan
        for (int i = tid; i < NBINS; i += 256)
            dst[i] = src[i] + ((i + off < NBINS) ? src[i + off] : 0u);
        __syncthreads();
        u32* t = src; src = dst; dst = t;
    }
    for (int i = tid; i < NBINS; i += 256) bh[(size_t)bb * NBINS + i] = src[i];
}

// ---------------- K2: WIDE column-sum of slice suffix-hists -> partials ----------------
__global__ __launch_bounds__(64) void k_red(const u32* __restrict__ bh, u32* __restrict__ part) {
    int blk = blockIdx.x, tid = threadIdx.x;      // grid = BB*RED*9, block = 64
    int b = blk / (RED * 9);
    int r = (blk / 9) % RED;
    int g = blk % 9;
    int f = g * 64 + tid;                          // < 576
    int s0 = r * RCH, s1 = s0 + RCH; if (s1 > SB) s1 = SB;
    const u32* base = bh + (size_t)(b * SB + s0) * NBINS + f;
    u32 acc = 0;
    int n = s1 - s0;
    #pragma unroll 8
    for (int s = 0; s < n; ++s) acc += base[(size_t)s * NBINS];
    part[(size_t)(b * RED + r) * NBINS + f] = acc;
}

// ---------------- K3 (fused scanoff+scatter): per-block threshold + own offset + scatter ----------------
__global__ __launch_bounds__(256) void k_scatterT(const u32* __restrict__ key, const u32* __restrict__ part,
                                                  const u32* __restrict__ bh, u32* __restrict__ cnt,
                                                  u64* __restrict__ cand) {
    __shared__ u32 tot[NBINS];
    __shared__ u32 wtot[4];
    __shared__ u32 sTf;
    int bb = blockIdx.x, tid = threadIdx.x;       // grid = BB*SB
    int b = bb / SB, c = bb % SB;
    int lane = tid & 63, wv = tid >> 6;
    for (int f = tid; f < NBINS; f += 256) {
        u32 x = 0;
        #pragma unroll
        for (int r = 0; r < RED; ++r) x += part[(size_t)(b * RED + r) * NBINS + f];
        tot[f] = x;                                // suffix count >= bin f
    }
    __syncthreads();
    u32 tv = tot[0];
    u32 target = (tv < K_PRE) ? tv : K_PRE;
    if (target == 0) {
        if (c == 0 && tid == 0) cnt[b] = 0;
        return;
    }
    for (int f = tid; f < NBINS; f += 256) {       // tot non-increasing -> unique crossing
        u32 cge = tot[f];
        u32 cnx = (f + 1 < NBINS) ? tot[f + 1] : 0u;
        if (cge >= target && cnx < target) sTf = (u32)f;
    }
    __syncthreads();
    u32 Tf = sTf;
    if (c == 0 && tid == 0) cnt[b] = tot[Tf];
    u32 m = 0;
    if (tid < c) m = bh[(size_t)(b * SB + tid) * NBINS + Tf];
    if (tid + 256 < c) m += bh[(size_t)(b * SB + tid + 256) * NBINS + Tf];
    #pragma unroll
    for (int o = 32; o > 0; o >>= 1) m += __shfl_down(m, o);
    if (lane == 0) wtot[wv] = m;
    __syncthreads();
    u32 boffc = wtot[0] + wtot[1] + wtot[2] + wtot[3];
    __syncthreads();
    u32 T16 = BIN0 + Tf;
    int a0 = c * CH2 + tid * 4;
    uint4 kk = make_uint4(0u, 0u, 0u, 0u);
    if (a0 < NN) kk = *((const uint4*)(key + (size_t)b * NN + a0));
    u32 ks[4] = {kk.x, kk.y, kk.z, kk.w};
    u32 f4[4];
    #pragma unroll
    for (int e = 0; e < 4; ++e) f4[e] = (u32)((ks[e] != 0) && ((ks[e] >> 16) >= T16));
    u32 tc = f4[0] + f4[1] + f4[2] + f4[3];
    u32 x = tc;
    #pragma unroll
    for (int o = 1; o < 64; o <<= 1) {
        u32 y = __shfl_up(x, o);
        if (lane >= o) x += y;
    }
    if (lane == 63) wtot[wv] = x;
    __syncthreads();
    u32 base = 0;
    { u32 w0 = wtot[0], w1 = wtot[1], w2 = wtot[2];
      if (wv > 0) base += w0; if (wv > 1) base += w1; if (wv > 2) base += w2; }
    u32 pos = boffc + base + x - tc;
    u64* cb = cand + (size_t)b * CAP;
    #pragma unroll
    for (int e = 0; e < 4; ++e) {
        if (f4[e]) {
            if (pos < CAP) cb[pos] = ((u64)(~ks[e]) << 32) | (u64)(a0 + e);
            ++pos;
        }
    }
}

// ---------------- K4: rank (dense permutation, keys unique) + decode fused ----------------
__global__ __launch_bounds__(256) void k_rankdec(const u32* __restrict__ cnt, const u64* __restrict__ cand,
                                                 const float* __restrict__ boxp, const float* __restrict__ cls,
                                                 const float* __restrict__ dirp, const float* __restrict__ anch,
                                                 float* __restrict__ tks, u32* __restrict__ meta,
                                                 float* __restrict__ box7, float* __restrict__ cor) {
    __shared__ u64 ck[CAP];                       // 32 KB
    int blk = blockIdx.x, tid = threadIdx.x;      // grid = BB*16
    int b = blk >> 4, rb = blk & 15;
    u32 nc = cnt[b]; if (nc > CAP) nc = CAP;
    int ci = rb * 256 + tid;
    if (rb * 256 >= (int)nc && rb * 256 >= K_PRE) return;
    const u64* cb = cand + (size_t)b * CAP;
    for (int i = tid; i < (int)nc; i += 256) ck[i] = cb[i];
    __syncthreads();

    int rank = -1; u32 idx = 0xFFFFFFFFu;
    if (ci < (int)nc) {
        u64 my = ck[ci];
        u32 r = 0;
        int j = 0;
        int nlim = (int)nc & ~15;
        for (; j < nlim; j += 16) {               // 16 independent LDS broadcast reads in flight
            u64 v0 = ck[j+0], v1 = ck[j+1], v2 = ck[j+2], v3 = ck[j+3];
            u64 v4 = ck[j+4], v5 = ck[j+5], v6 = ck[j+6], v7 = ck[j+7];
            u64 v8 = ck[j+8], v9 = ck[j+9], va = ck[j+10], vb = ck[j+11];
            u64 vc = ck[j+12], vd = ck[j+13], ve = ck[j+14], vf = ck[j+15];
            r += (u32)(v0 < my) + (u32)(v1 < my) + (u32)(v2 < my) + (u32)(v3 < my)
               + (u32)(v4 < my) + (u32)(v5 < my) + (u32)(v6 < my) + (u32)(v7 < my)
               + (u32)(v8 < my) + (u32)(v9 < my) + (u32)(va < my) + (u32)(vb < my)
               + (u32)(vc < my) + (u32)(vd < my) + (u32)(ve < my) + (u32)(vf < my);
        }
        for (; j < (int)nc; ++j) r += (u32)(ck[j] < my);
        if (r < K_PRE) { rank = (int)r; idx = (u32)my; }
    } else if (ci < K_PRE) {
        rank = ci;                                 // invalid-slot filler (disjoint from real ranks)
    }
    if (rank < 0) return;

    float ob[7] = {0,0,0,0,0,0,0};
    float c5[5] = {0,0,0,0,0};
    float sc = 0.f; u32 mt = 0;
    if (idx != 0xFFFFFFFFu) {
        const float* A = anch + (size_t)idx * 7;
        const float* D = boxp + ((size_t)b * NN + idx) * 7;
        float xa=A[0], ya=A[1], za=A[2], wa=A[3], la=A[4], ha=A[5], ra=A[6];
        float xt=D[0], yt=D[1], zt=D[2], wt=D[3], lt=D[4], ht=D[5], rt=D[6];
        za = za + ha * 0.5f;
        float diag = sqrtf(la * la + wa * wa);
        float xg = xt * diag + xa;
        float yg = yt * diag + ya;
        float zg = zt * ha + za;
        float wg = expf(wt) * wa;
        float lg = expf(lt) * la;
        float hg = expf(ht) * ha;
        zg = zg - hg * 0.5f;
        float rg = rt + ra;
        ob[0]=xg; ob[1]=yg; ob[2]=zg; ob[3]=wg; ob[4]=lg; ob[5]=hg; ob[6]=rg;
        float cr = fabsf(cosf(rg)), sr = fabsf(sinf(rg));
        float hx = 0.5f * (wg * cr + lg * sr);
        float hy = 0.5f * (wg * sr + lg * cr);
        float x1 = xg - hx, x2 = xg + hx, y1 = yg - hy, y2 = yg + hy;
        c5[0]=x1; c5[1]=x2; c5[2]=y1; c5[3]=y2; c5[4]=(x2-x1)*(y2-y1);
        const float* cc = cls + ((size_t)b * NN + idx) * 3;
        float p0 = sigm(cc[0]), p1 = sigm(cc[1]), p2 = sigm(cc[2]);
        int lbl = 0; float best = p0;
        if (p1 > best) { best = p1; lbl = 1; }
        if (p2 > best) { best = p2; lbl = 2; }
        sc = best;
        const float* dd = dirp + ((size_t)b * NN + idx) * 2;
        int dl = (dd[1] > dd[0]) ? 1 : 0;
        mt = (u32)lbl | ((u32)dl << 8) | (1u << 16);
    }
    size_t t = (size_t)b * K_PRE + rank;
    tks[t] = sc; meta[t] = mt;
    #pragma unroll
    for (int j = 0; j < 7; ++j) box7[t * 7 + j] = ob[j];
    #pragma unroll
    for (int j = 0; j < 5; ++j) cor[t * 5 + j] = c5[j];
}

// ---------------- K5: TRANSPOSED suppression bitmask (LDS-staged boxes) ----------------
__global__ __launch_bounds__(256) void k_maskT(const float* __restrict__ cor, u64* __restrict__ maskT) {
    __shared__ float s4[(K_PRE + 16) * 4];        // index i+(i>>6) breaks bank conflicts
    __shared__ float sA[K_PRE + 16];
    int blk = blockIdx.x;                         // grid = BB * 63
    int b = blk / 63, jb = blk % 63;
    int tid = threadIdx.x;
    const float4* C4 = (const float4*)(cor + (size_t)b * K_PRE * 5);
    for (int q = tid; q < (K_PRE * 5) / 4; q += 256) {
        float4 v = C4[q];
        int t0 = q * 4;
        #pragma unroll
        for (int e = 0; e < 4; ++e) {
            int t = t0 + e;
            int i = t / 5, k = t - i * 5;
            float val = (e == 0) ? v.x : (e == 1) ? v.y : (e == 2) ? v.z : v.w;
            int ip = i + (i >> 6);
            if (k < 4) s4[ip * 4 + k] = val; else sA[ip] = val;
        }
    }
    __syncthreads();
    int w = tid & 15, jl = tid >> 4;
    int j = jb * 16 + jl;
    if (j >= K_PRE) return;
    int jp = j + (j >> 6);
    float x1 = s4[jp*4+0], x2 = s4[jp*4+1], y1 = s4[jp*4+2], y2 = s4[jp*4+3], ar = sA[jp];
    u64 m = 0;
    int i0 = w * 64;
    if (i0 < j) {
        int iend = j - i0; if (iend > 64) iend = 64;
        for (int ii = 0; ii < iend; ++ii) {
            int i = i0 + ii;
            int ip = i + (i >> 6);
            float4 bx = *(const float4*)&s4[ip * 4];
            float ai = sA[ip];
            float ix = fminf(x2, bx.y) - fmaxf(x1, bx.x); ix = fmaxf(ix, 0.f);
            float iy = fminf(y2, bx.w) - fmaxf(y1, bx.z); iy = fmaxf(iy, 0.f);
            float inter = ix * iy;
            float uni = ai + ar - inter;              // fp-add commutative == ref order
            float iou = (uni > 0.f) ? inter / fmaxf(uni, 1e-12f) : 0.f;
            if (iou > IOU_THR) m |= (1ull << ii);
        }
    }
    maskT[((size_t)b * K_PRE + j) * NW + w] = m;
}

// in-wave 64x64 bit-matrix transpose: lane j holds row j (bit i) -> lane l holds col l (bit j)
__device__ __forceinline__ u64 bit_transpose64(u64 x, int lane) {
    #pragma unroll
    for (int k = 0; k < 6; ++k) {
        const int s = 32 >> k;
        const u64 Mhi = (k == 0) ? 0xFFFFFFFF00000000ull :
                        (k == 1) ? 0xFFFF0000FFFF0000ull :
                        (k == 2) ? 0xFF00FF00FF00FF00ull :
                        (k == 3) ? 0xF0F0F0F0F0F0F0F0ull :
                        (k == 4) ? 0xCCCCCCCCCCCCCCCCull : 0xAAAAAAAAAAAAAAAAull;
        u64 y = (u64)__shfl_xor((long long)x, s);
        if ((lane & s) == 0) x = (x & ~Mhi) | ((y << s) & Mhi);
        else                 x = (x & Mhi) | ((y >> s) & ~Mhi);
    }
    return x;
}

// ---------------- K6: greedy NMS — branchless 64-step unrolled SALU chain per chunk ----------------
__global__ __launch_bounds__(256) void k_nms_out(const u32* __restrict__ meta, const float* __restrict__ box7,
                                                 const float* __restrict__ tks, const u64* __restrict__ maskT,
                                                 float* __restrict__ out) {
    int b = blockIdx.x; int tid = threadIdx.x;
    int lane = tid & 63, wvi = tid >> 6;
    __shared__ u64 mrow[64 * 17];                 // transpose buffer, +1-row pad
    __shared__ u64 vb_s[16];                      // validity bitmap (1000 bits)
    __shared__ u64 km_s[16];                      // kept-bits per chunk (wave-0 private)
    __shared__ int sel_s[K_POST];
    __shared__ int cnt_s;
    const u32* M = meta + b * K_PRE;
    const u64* Mk = maskT + (size_t)b * K_PRE * NW;

    // validity bitmap: 4 coalesced rounds of ballot
    for (int base = 0; base < K_PRE; base += 256) {
        int slot = base + tid;
        bool v = (slot < K_PRE) && ((M[slot] >> 16) & 1u);
        u64 word = __ballot(v);
        if (lane == 0) vb_s[(base >> 6) + wvi] = word;
    }
    if (tid < 16) km_s[tid] = 0ull;
    __syncthreads();

    if (tid < 64) {                               // wave 0 runs the whole greedy chain
        int wsel = lane & 15, rq = lane >> 4;     // word select / row quarter
        int cnt = 0;
        for (int c = 0; c < 16 && cnt < K_POST; ++c) {
            // coalesced load of chunk c (64 rows x 16 u64): instr k covers 4 rows = 512 B contiguous
            u64 v[16];
            #pragma unroll
            for (int k = 0; k < 16; ++k) {
                int row = c * 64 + k * 4 + rq;
                int rc = (row < K_PRE) ? row : (K_PRE - 1);   // clamped rows are invalid anyway
                v[k] = Mk[(size_t)rc * NW + wsel];
            }
            #pragma unroll
            for (int k = 0; k < 16; ++k)
                mrow[(k * 4 + rq) * 17 + wsel] = v[k];        // transpose via LDS (same wave)
            u64 cw = 0;
            u64 supacc = 0;
            #pragma unroll
            for (int w = 0; w < 16; ++w) {
                u64 mv = mrow[lane * 17 + w];
                supacc |= (mv & km_s[w]);                      // km_s[w]=0 for w>=c
                if (w == c) cw = mv;
            }
            // per-lane column mask: bit j = "my box (lane) suppresses box j of this chunk"
            u64 colmask = bit_transpose64(cw, lane);
            u32 clo_all = (u32)(colmask & 0xFFFFFFFFull);
            u32 chi_all = (u32)(colmask >> 32);
            int j = c * 64 + lane;
            bool jvalid = (j < K_PRE) && (((vb_s[c] >> lane) & 1ull) != 0ull);
            u64 active = __ballot(jvalid && (supacc == 0ull));
            // branchless unrolled greedy: ascending i == ffs order; col bits only point forward
            u64 kmc = 0ull;
            #pragma unroll
            for (int i = 0; i < 64; ++i) {
                u64 bit = 1ull << i;
                bool kp = (active & bit) != 0ull;              // wave-uniform SCC
                u32 cl = (u32)__builtin_amdgcn_readlane((int)clo_all, i);  // immediate lane
                u32 ch = (u32)__builtin_amdgcn_readlane((int)chi_all, i);
                u64 col = ((u64)ch << 32) | (u64)cl;
                kmc |= kp ? bit : 0ull;                        // s_cselect + s_or
                active &= ~(kp ? col : 0ull);                  // s_cselect + s_andn2
            }
            km_s[c] = kmc;                                     // wave-0 write/read only
            // lane-parallel expansion of kept set into sel_s (keep order == ascending bit order)
            if ((kmc >> lane) & 1ull) {
                int pos = cnt + (int)__popcll(kmc & ((lane == 0) ? 0ull : ((~0ull) >> (64 - lane))));
                if (pos < K_POST) sel_s[pos] = c * 64 + lane;
            }
            cnt += (int)__popcll(kmc);
        }
        if (lane == 0) cnt_s = (cnt < K_POST) ? cnt : K_POST;
    }
    __syncthreads();

    int kept = cnt_s;
    const float* BX = box7 + (size_t)b * K_PRE * 7;
    const float* SS = tks + b * K_PRE;
    for (int p = tid; p < K_POST; p += 256) {
        float ob[7] = {0,0,0,0,0,0,0};
        float sc = 0.f, lb = 0.f, vd2 = 0.f;
        if (p < kept) {
            int i = sel_s[p];
            float xg = BX[i*7+0], yg = BX[i*7+1], zg = BX[i*7+2];
            bool in_range = (xg >= 0.0f) && (xg <= 69.12f) &&
                            (yg >= -39.68f) && (yg <= 39.68f) &&
                            (zg >= -5.0f) && (zg <= 5.0f);
            if (in_range) {
                u32 mt = M[i];
                int dl = (mt >> 8) & 0xFF;
                float r = BX[i*7+6];
                bool opp = ((r > 0.0f) != (dl == 1));
                float rf = r + (opp ? 3.14159274f : 0.0f);
                ob[0]=xg; ob[1]=yg; ob[2]=zg; ob[3]=BX[i*7+3]; ob[4]=BX[i*7+4]; ob[5]=BX[i*7+5]; ob[6]=rf;
                sc = SS[i]; lb = (float)(mt & 0xFF); vd2 = 1.0f;
            }
        }
        size_t ro = (size_t)(b * K_POST + p);
        #pragma unroll
        for (int j = 0; j < 7; ++j) out[ro * 7 + j] = ob[j];
        out[(size_t)BB * K_POST * 7 + ro] = lb;   // labels
        out[(size_t)BB * K_POST * 8 + ro] = sc;   // scores
        out[(size_t)BB * K_POST * 9 + ro] = vd2;  // valid
    }
}

extern "C" void kernel_launch(void* const* d_in, const int* in_sizes, int n_in,
                              void* d_out, int out_size, void* d_ws, size_t ws_size,
                              hipStream_t stream) {
    const float* boxp = (const float*)d_in[0];
    const float* cls  = (const float*)d_in[1];
    const float* dirp = (const float*)d_in[2];
    const float* anch = (const float*)d_in[3];
    float* out = (float*)d_out;

    char* p = (char*)d_ws;
    u32* key  = (u32*)p; p += (size_t)BB * NN * 4;
    u32* bh   = (u32*)p; p += (size_t)BB * SB * NBINS * 4;   // suffix-hist slices
    u32* part = (u32*)p; p += (size_t)BB * RED * NBINS * 4;  // column-sum partials
    u32* cnt  = (u32*)p; p += 256;
    u64* cand = (u64*)p; p += (size_t)BB * CAP * 8;
    float* tks = (float*)p; p += (size_t)BB * K_PRE * 4;
    u32* meta = (u32*)p; p += (size_t)BB * K_PRE * 4;
    float* box7 = (float*)p; p += (size_t)BB * K_PRE * 7 * 4;
    float* cor  = (float*)p; p += (size_t)BB * K_PRE * 5 * 4;
    u64* maskT = (u64*)p; p += (size_t)BB * K_PRE * NW * 8;

    k_score_hist<<<BB * SB, 256, 0, stream>>>(cls, key, bh);
    k_red<<<BB * RED * 9, 64, 0, stream>>>(bh, part);
    k_scatterT<<<BB * SB, 256, 0, stream>>>(key, part, bh, cnt, cand);
    k_rankdec<<<BB * 16, 256, 0, stream>>>(cnt, cand, boxp, cls, dirp, anch, tks, meta, box7, cor);
    k_maskT<<<BB * 63, 256, 0, stream>>>(cor, maskT);
    k_nms_out<<<BB, 256, 0, stream>>>(meta, box7, tks, maskT, out);
}

// Round 21
// 74.369 us; speedup vs baseline: 1.2416x; 1.0185x over previous
//
#include <hip/hip_runtime.h>
#include <stdint.h>

typedef unsigned long long u64;
typedef unsigned int u32;

#define BB 4
#define NN 321408
#define K_PRE 1000
#define K_POST 300
#define CAP 4096
#define NW 16                 // 1000 bits -> 16 u64 words
#define SCORE_THR 0.05f
#define IOU_THR 0.5f
#define SB 157                // slice blocks per batch (ceil(NN/2048))
#define CH2 2048              // anchors per slice block (8 per thread)
#define NBINS 576             // 16-bit key prefixes span 0xBD4C..0xBF80 (s in [0.05,1.0])
#define BIN0 0xBD4Cu
#define RED 8                 // wide 2-stage reduce (NEVER 4-block serial — R7/R11 lesson)
#define RCH 20                // slices per chunk (8*20 >= 157)

__device__ __forceinline__ float sigm(float x) { return 1.0f / (1.0f + expf(-x)); }

__device__ __forceinline__ u32 mkkey(float mx) {
    float s = sigm(mx);
    return (s >= SCORE_THR) ? (__float_as_uint(s) | 0x80000000u) : 0u;
}

__device__ __forceinline__ void quadkeys(const float* cls, size_t base, uint4& o) {
    const float4* c4 = (const float4*)(cls + base * 3);
    float4 v0 = c4[0], v1 = c4[1], v2 = c4[2];
    o.x = mkkey(fmaxf(v0.x, fmaxf(v0.y, v0.z)));
    o.y = mkkey(fmaxf(v0.w, fmaxf(v1.x, v1.y)));
    o.z = mkkey(fmaxf(v1.z, fmaxf(v1.w, v2.x)));
    o.w = mkkey(fmaxf(v2.y, fmaxf(v2.z, v2.w)));
}

// ---------------- K1: keys + 576-bin LDS hist (2048 anchors/slice), SUFFIX-cumulative ----------------
__global__ void k_score_hist(const float* __restrict__ cls, u32* __restrict__ key, u32* __restrict__ bh) {
    __shared__ u32 h1[NBINS], h2[NBINS];
    int bb = blockIdx.x, tid = threadIdx.x;       // grid = BB*SB
    int b = bb / SB, c = bb % SB;
    for (int i = tid; i < NBINS; i += 256) h1[i] = 0;
    __syncthreads();
    int a0 = c * CH2 + tid * 4;                   // first quad
    int a1 = a0 + 1024;                           // second quad (NN % 4 == 0)
    if (a0 < NN) {
        uint4 o; quadkeys(cls, (size_t)b * NN + a0, o);
        *((uint4*)(key + (size_t)b * NN + a0)) = o;
        if (o.x) atomicAdd(&h1[min((o.x >> 16) - BIN0, (u32)(NBINS - 1))], 1u);
        if (o.y) atomicAdd(&h1[min((o.y >> 16) - BIN0, (u32)(NBINS - 1))], 1u);
        if (o.z) atomicAdd(&h1[min((o.z >> 16) - BIN0, (u32)(NBINS - 1))], 1u);
        if (o.w) atomicAdd(&h1[min((o.w >> 16) - BIN0, (u32)(NBINS - 1))], 1u);
    }
    if (a1 < NN) {
        uint4 o; quadkeys(cls, (size_t)b * NN + a1, o);
        *((uint4*)(key + (size_t)b * NN + a1)) = o;
        if (o.x) atomicAdd(&h1[min((o.x >> 16) - BIN0, (u32)(NBINS - 1))], 1u);
        if (o.y) atomicAdd(&h1[min((o.y >> 16) - BIN0, (u32)(NBINS - 1))], 1u);
        if (o.z) atomicAdd(&h1[min((o.z >> 16) - BIN0, (u32)(NBINS - 1))], 1u);
        if (o.w) atomicAdd(&h1[min((o.w >> 16) - BIN0, (u32)(NBINS - 1))], 1u);
    }
    __syncthreads();
    u32* src = h1; u32* dst = h2;
    for (int off = 1; off < NBINS; off <<= 1) {   // 10-pass suffix scan
        for (int i = tid; i < NBINS; i += 256)
            dst[i] = src[i] + ((i + off < NBINS) ? src[i + off] : 0u);
        __syncthreads();
        u32* t = src; src = dst; dst = t;
    }
    for (int i = tid; i < NBINS; i += 256) bh[(size_t)bb * NBINS + i] = src[i];
}

// ---------------- K2: WIDE column-sum of slice suffix-hists -> partials ----------------
__global__ __launch_bounds__(64) void k_red(const u32* __restrict__ bh, u32* __restrict__ part) {
    int blk = blockIdx.x, tid = threadIdx.x;      // grid = BB*RED*9, block = 64
    int b = blk / (RED * 9);
    int r = (blk / 9) % RED;
    int g = blk % 9;
    int f = g * 64 + tid;                          // < 576
    int s0 = r * RCH, s1 = s0 + RCH; if (s1 > SB) s1 = SB;
    const u32* base = bh + (size_t)(b * SB + s0) * NBINS + f;
    u32 acc = 0;
    int n = s1 - s0;
    #pragma unroll 5
    for (int s = 0; s < n; ++s) acc += base[(size_t)s * NBINS];
    part[(size_t)(b * RED + r) * NBINS + f] = acc;
}

// ---------------- K3 (fused scanoff+scatter): per-block threshold + own offset + scatter ----------------
__global__ __launch_bounds__(256) void k_scatterT(const u32* __restrict__ key, const u32* __restrict__ part,
                                                  const u32* __restrict__ bh, u32* __restrict__ cnt,
                                                  u64* __restrict__ cand) {
    __shared__ u32 tot[NBINS];
    __shared__ u32 wtot[4];
    __shared__ u32 sTf;
    int bb = blockIdx.x, tid = threadIdx.x;       // grid = BB*SB
    int b = bb / SB, c = bb % SB;
    int lane = tid & 63, wv = tid >> 6;
    for (int f = tid; f < NBINS; f += 256) {
        u32 x = 0;
        #pragma unroll
        for (int r = 0; r < RED; ++r) x += part[(size_t)(b * RED + r) * NBINS + f];
        tot[f] = x;                                // suffix count >= bin f
    }
    __syncthreads();
    u32 tv = tot[0];
    u32 target = (tv < K_PRE) ? tv : K_PRE;
    if (target == 0) {
        if (c == 0 && tid == 0) cnt[b] = 0;
        return;
    }
    for (int f = tid; f < NBINS; f += 256) {       // tot non-increasing -> unique crossing
        u32 cge = tot[f];
        u32 cnx = (f + 1 < NBINS) ? tot[f + 1] : 0u;
        if (cge >= target && cnx < target) sTf = (u32)f;
    }
    __syncthreads();
    u32 Tf = sTf;
    if (c == 0 && tid == 0) cnt[b] = tot[Tf];
    // own exclusive offset: sum of per-slice suffix counts for slices < c (SB=157 < 256: one round)
    u32 m = 0;
    if (tid < c) m = bh[(size_t)(b * SB + tid) * NBINS + Tf];
    #pragma unroll
    for (int o = 32; o > 0; o >>= 1) m += __shfl_down(m, o);
    if (lane == 0) wtot[wv] = m;
    __syncthreads();
    u32 boffc = wtot[0] + wtot[1] + wtot[2] + wtot[3];
    __syncthreads();                               // wtot reused below
    u32 T16 = BIN0 + Tf;
    int a0 = c * CH2 + tid * 4;
    int a1 = a0 + 1024;
    uint4 k0 = make_uint4(0u, 0u, 0u, 0u), k1 = make_uint4(0u, 0u, 0u, 0u);
    if (a0 < NN) k0 = *((const uint4*)(key + (size_t)b * NN + a0));
    if (a1 < NN) k1 = *((const uint4*)(key + (size_t)b * NN + a1));
    u32 ks[8] = {k0.x, k0.y, k0.z, k0.w, k1.x, k1.y, k1.z, k1.w};
    u32 f8[8];
    #pragma unroll
    for (int e = 0; e < 8; ++e) f8[e] = (u32)((ks[e] != 0) && ((ks[e] >> 16) >= T16));
    u32 tc = 0;
    #pragma unroll
    for (int e = 0; e < 8; ++e) tc += f8[e];
    u32 x = tc;
    #pragma unroll
    for (int o = 1; o < 64; o <<= 1) {
        u32 y = __shfl_up(x, o);
        if (lane >= o) x += y;
    }
    if (lane == 63) wtot[wv] = x;
    __syncthreads();
    u32 base = 0;
    { u32 w0 = wtot[0], w1 = wtot[1], w2 = wtot[2];
      if (wv > 0) base += w0; if (wv > 1) base += w1; if (wv > 2) base += w2; }
    u32 pos = boffc + base + x - tc;
    u64* cb = cand + (size_t)b * CAP;
    #pragma unroll
    for (int e = 0; e < 8; ++e) {
        if (f8[e]) {
            int ai = (e < 4) ? (a0 + e) : (a1 + e - 4);
            // candidate SET only; order irrelevant (rank phase sorts by key)
            if (pos < CAP) cb[pos] = ((u64)(~ks[e]) << 32) | (u64)ai;
            ++pos;
        }
    }
}

// ---------------- K4: rank (dense permutation, keys unique) + decode fused ----------------
__global__ __launch_bounds__(256) void k_rankdec(const u32* __restrict__ cnt, const u64* __restrict__ cand,
                                                 const float* __restrict__ boxp, const float* __restrict__ cls,
                                                 const float* __restrict__ dirp, const float* __restrict__ anch,
                                                 float* __restrict__ tks, u32* __restrict__ meta,
                                                 float* __restrict__ box7, float* __restrict__ cor) {
    __shared__ u64 ck[CAP];                       // 32 KB
    int blk = blockIdx.x, tid = threadIdx.x;      // grid = BB*16
    int b = blk >> 4, rb = blk & 15;
    u32 nc = cnt[b]; if (nc > CAP) nc = CAP;
    int ci = rb * 256 + tid;
    if (rb * 256 >= (int)nc && rb * 256 >= K_PRE) return;
    const u64* cb = cand + (size_t)b * CAP;
    for (int i = tid; i < (int)nc; i += 256) ck[i] = cb[i];
    __syncthreads();

    int rank = -1; u32 idx = 0xFFFFFFFFu;
    if (ci < (int)nc) {
        u64 my = ck[ci];
        u32 r = 0;
        int j = 0;
        int nlim = (int)nc & ~15;
        for (; j < nlim; j += 16) {               // 16 independent LDS broadcast reads in flight
            u64 v0 = ck[j+0], v1 = ck[j+1], v2 = ck[j+2], v3 = ck[j+3];
            u64 v4 = ck[j+4], v5 = ck[j+5], v6 = ck[j+6], v7 = ck[j+7];
            u64 v8 = ck[j+8], v9 = ck[j+9], va = ck[j+10], vb = ck[j+11];
            u64 vc = ck[j+12], vd = ck[j+13], ve = ck[j+14], vf = ck[j+15];
            r += (u32)(v0 < my) + (u32)(v1 < my) + (u32)(v2 < my) + (u32)(v3 < my)
               + (u32)(v4 < my) + (u32)(v5 < my) + (u32)(v6 < my) + (u32)(v7 < my)
               + (u32)(v8 < my) + (u32)(v9 < my) + (u32)(va < my) + (u32)(vb < my)
               + (u32)(vc < my) + (u32)(vd < my) + (u32)(ve < my) + (u32)(vf < my);
        }
        for (; j < (int)nc; ++j) r += (u32)(ck[j] < my);
        if (r < K_PRE) { rank = (int)r; idx = (u32)my; }
    } else if (ci < K_PRE) {
        rank = ci;                                 // invalid-slot filler (disjoint from real ranks)
    }
    if (rank < 0) return;

    float ob[7] = {0,0,0,0,0,0,0};
    float c5[5] = {0,0,0,0,0};
    float sc = 0.f; u32 mt = 0;
    if (idx != 0xFFFFFFFFu) {
        const float* A = anch + (size_t)idx * 7;
        const float* D = boxp + ((size_t)b * NN + idx) * 7;
        float xa=A[0], ya=A[1], za=A[2], wa=A[3], la=A[4], ha=A[5], ra=A[6];
        float xt=D[0], yt=D[1], zt=D[2], wt=D[3], lt=D[4], ht=D[5], rt=D[6];
        za = za + ha * 0.5f;
        float diag = sqrtf(la * la + wa * wa);
        float xg = xt * diag + xa;
        float yg = yt * diag + ya;
        float zg = zt * ha + za;
        float wg = expf(wt) * wa;
        float lg = expf(lt) * la;
        float hg = expf(ht) * ha;
        zg = zg - hg * 0.5f;
        float rg = rt + ra;
        ob[0]=xg; ob[1]=yg; ob[2]=zg; ob[3]=wg; ob[4]=lg; ob[5]=hg; ob[6]=rg;
        float cr = fabsf(cosf(rg)), sr = fabsf(sinf(rg));
        float hx = 0.5f * (wg * cr + lg * sr);
        float hy = 0.5f * (wg * sr + lg * cr);
        float x1 = xg - hx, x2 = xg + hx, y1 = yg - hy, y2 = yg + hy;
        c5[0]=x1; c5[1]=x2; c5[2]=y1; c5[3]=y2; c5[4]=(x2-x1)*(y2-y1);
        const float* cc = cls + ((size_t)b * NN + idx) * 3;
        float p0 = sigm(cc[0]), p1 = sigm(cc[1]), p2 = sigm(cc[2]);
        int lbl = 0; float best = p0;
        if (p1 > best) { best = p1; lbl = 1; }
        if (p2 > best) { best = p2; lbl = 2; }
        sc = best;
        const float* dd = dirp + ((size_t)b * NN + idx) * 2;
        int dl = (dd[1] > dd[0]) ? 1 : 0;
        mt = (u32)lbl | ((u32)dl << 8) | (1u << 16);
    }
    size_t t = (size_t)b * K_PRE + rank;
    tks[t] = sc; meta[t] = mt;
    #pragma unroll
    for (int j = 0; j < 7; ++j) box7[t * 7 + j] = ob[j];
    #pragma unroll
    for (int j = 0; j < 5; ++j) cor[t * 5 + j] = c5[j];
}

// ---------------- K5: TRANSPOSED suppression bitmask (LDS-staged boxes) ----------------
__global__ __launch_bounds__(256) void k_maskT(const float* __restrict__ cor, u64* __restrict__ maskT) {
    __shared__ float s4[(K_PRE + 16) * 4];        // index i+(i>>6) breaks bank conflicts
    __shared__ float sA[K_PRE + 16];
    int blk = blockIdx.x;                         // grid = BB * 63
    int b = blk / 63, jb = blk % 63;
    int tid = threadIdx.x;
    const float4* C4 = (const float4*)(cor + (size_t)b * K_PRE * 5);
    for (int q = tid; q < (K_PRE * 5) / 4; q += 256) {
        float4 v = C4[q];
        int t0 = q * 4;
        #pragma unroll
        for (int e = 0; e < 4; ++e) {
            int t = t0 + e;
            int i = t / 5, k = t - i * 5;
            float val = (e == 0) ? v.x : (e == 1) ? v.y : (e == 2) ? v.z : v.w;
            int ip = i + (i >> 6);
            if (k < 4) s4[ip * 4 + k] = val; else sA[ip] = val;
        }
    }
    __syncthreads();
    int w = tid & 15, jl = tid >> 4;
    int j = jb * 16 + jl;
    if (j >= K_PRE) return;
    int jp = j + (j >> 6);
    float x1 = s4[jp*4+0], x2 = s4[jp*4+1], y1 = s4[jp*4+2], y2 = s4[jp*4+3], ar = sA[jp];
    u64 m = 0;
    int i0 = w * 64;
    if (i0 < j) {
        int iend = j - i0; if (iend > 64) iend = 64;
        for (int ii = 0; ii < iend; ++ii) {
            int i = i0 + ii;
            int ip = i + (i >> 6);
            float4 bx = *(const float4*)&s4[ip * 4];
            float ai = sA[ip];
            float ix = fminf(x2, bx.y) - fmaxf(x1, bx.x); ix = fmaxf(ix, 0.f);
            float iy = fminf(y2, bx.w) - fmaxf(y1, bx.z); iy = fmaxf(iy, 0.f);
            float inter = ix * iy;
            float uni = ai + ar - inter;              // fp-add commutative == ref order
            float iou = (uni > 0.f) ? inter / fmaxf(uni, 1e-12f) : 0.f;
            if (iou > IOU_THR) m |= (1ull << ii);
        }
    }
    maskT[((size_t)b * K_PRE + j) * NW + w] = m;
}

// in-wave 64x64 bit-matrix transpose: lane j holds row j (bit i) -> lane l holds col l (bit j)
__device__ __forceinline__ u64 bit_transpose64(u64 x, int lane) {
    #pragma unroll
    for (int k = 0; k < 6; ++k) {
        const int s = 32 >> k;
        const u64 Mhi = (k == 0) ? 0xFFFFFFFF00000000ull :
                        (k == 1) ? 0xFFFF0000FFFF0000ull :
                        (k == 2) ? 0xFF00FF00FF00FF00ull :
                        (k == 3) ? 0xF0F0F0F0F0F0F0F0ull :
                        (k == 4) ? 0xCCCCCCCCCCCCCCCCull : 0xAAAAAAAAAAAAAAAAull;
        u64 y = (u64)__shfl_xor((long long)x, s);
        if ((lane & s) == 0) x = (x & ~Mhi) | ((y << s) & Mhi);
        else                 x = (x & Mhi) | ((y >> s) & ~Mhi);
    }
    return x;
}

// ---------------- K6: greedy NMS — branchless 64-step unrolled SALU chain per chunk ----------------
__global__ __launch_bounds__(256) void k_nms_out(const u32* __restrict__ meta, const float* __restrict__ box7,
                                                 const float* __restrict__ tks, const u64* __restrict__ maskT,
                                                 float* __restrict__ out) {
    int b = blockIdx.x; int tid = threadIdx.x;
    int lane = tid & 63, wvi = tid >> 6;
    __shared__ u64 mrow[64 * 17];                 // transpose buffer, +1-row pad
    __shared__ u64 vb_s[16];                      // validity bitmap (1000 bits)
    __shared__ u64 km_s[16];                      // kept-bits per chunk (wave-0 private)
    __shared__ int sel_s[K_POST];
    __shared__ int cnt_s;
    const u32* M = meta + b * K_PRE;
    const u64* Mk = maskT + (size_t)b * K_PRE * NW;

    // validity bitmap: 4 coalesced rounds of ballot
    for (int base = 0; base < K_PRE; base += 256) {
        int slot = base + tid;
        bool v = (slot < K_PRE) && ((M[slot] >> 16) & 1u);
        u64 word = __ballot(v);
        if (lane == 0) vb_s[(base >> 6) + wvi] = word;
    }
    if (tid < 16) km_s[tid] = 0ull;
    __syncthreads();

    if (tid < 64) {                               // wave 0 runs the whole greedy chain
        int wsel = lane & 15, rq = lane >> 4;     // word select / row quarter
        int cnt = 0;
        for (int c = 0; c < 16 && cnt < K_POST; ++c) {
            u64 v[16];
            #pragma unroll
            for (int k = 0; k < 16; ++k) {
                int row = c * 64 + k * 4 + rq;
                int rc = (row < K_PRE) ? row : (K_PRE - 1);   // clamped rows are invalid anyway
                v[k] = Mk[(size_t)rc * NW + wsel];
            }
            #pragma unroll
            for (int k = 0; k < 16; ++k)
                mrow[(k * 4 + rq) * 17 + wsel] = v[k];        // transpose via LDS (same wave)
            u64 cw = 0;
            u64 supacc = 0;
            #pragma unroll
            for (int w = 0; w < 16; ++w) {
                u64 mv = mrow[lane * 17 + w];
                supacc |= (mv & km_s[w]);                      // km_s[w]=0 for w>=c
                if (w == c) cw = mv;
            }
            u64 colmask = bit_transpose64(cw, lane);
            u32 clo_all = (u32)(colmask & 0xFFFFFFFFull);
            u32 chi_all = (u32)(colmask >> 32);
            int j = c * 64 + lane;
            bool jvalid = (j < K_PRE) && (((vb_s[c] >> lane) & 1ull) != 0ull);
            u64 active = __ballot(jvalid && (supacc == 0ull));
            u64 kmc = 0ull;
            #pragma unroll
            for (int i = 0; i < 64; ++i) {
                u64 bit = 1ull << i;
                bool kp = (active & bit) != 0ull;              // wave-uniform SCC
                u32 cl = (u32)__builtin_amdgcn_readlane((int)clo_all, i);  // immediate lane
                u32 ch = (u32)__builtin_amdgcn_readlane((int)chi_all, i);
                u64 col = ((u64)ch << 32) | (u64)cl;
                kmc |= kp ? bit : 0ull;
                active &= ~(kp ? col : 0ull);
            }
            km_s[c] = kmc;                                     // wave-0 write/read only
            if ((kmc >> lane) & 1ull) {
                int pos = cnt + (int)__popcll(kmc & ((lane == 0) ? 0ull : ((~0ull) >> (64 - lane))));
                if (pos < K_POST) sel_s[pos] = c * 64 + lane;
            }
            cnt += (int)__popcll(kmc);
        }
        if (lane == 0) cnt_s = (cnt < K_POST) ? cnt : K_POST;
    }
    __syncthreads();

    int kept = cnt_s;
    const float* BX = box7 + (size_t)b * K_PRE * 7;
    const float* SS = tks + b * K_PRE;
    for (int p = tid; p < K_POST; p += 256) {
        float ob[7] = {0,0,0,0,0,0,0};
        float sc = 0.f, lb = 0.f, vd2 = 0.f;
        if (p < kept) {
            int i = sel_s[p];
            float xg = BX[i*7+0], yg = BX[i*7+1], zg = BX[i*7+2];
            bool in_range = (xg >= 0.0f) && (xg <= 69.12f) &&
                            (yg >= -39.68f) && (yg <= 39.68f) &&
                            (zg >= -5.0f) && (zg <= 5.0f);
            if (in_range) {
                u32 mt = M[i];
                int dl = (mt >> 8) & 0xFF;
                float r = BX[i*7+6];
                bool opp = ((r > 0.0f) != (dl == 1));
                float rf = r + (opp ? 3.14159274f : 0.0f);
                ob[0]=xg; ob[1]=yg; ob[2]=zg; ob[3]=BX[i*7+3]; ob[4]=BX[i*7+4]; ob[5]=BX[i*7+5]; ob[6]=rf;
                sc = SS[i]; lb = (float)(mt & 0xFF); vd2 = 1.0f;
            }
        }
        size_t ro = (size_t)(b * K_POST + p);
        #pragma unroll
        for (int j = 0; j < 7; ++j) out[ro * 7 + j] = ob[j];
        out[(size_t)BB * K_POST * 7 + ro] = lb;   // labels
        out[(size_t)BB * K_POST * 8 + ro] = sc;   // scores
        out[(size_t)BB * K_POST * 9 + ro] = vd2;  // valid
    }
}

extern "C" void kernel_launch(void* const* d_in, const int* in_sizes, int n_in,
                              void* d_out, int out_size, void* d_ws, size_t ws_size,
                              hipStream_t stream) {
    const float* boxp = (const float*)d_in[0];
    const float* cls  = (const float*)d_in[1];
    const float* dirp = (const float*)d_in[2];
    const float* anch = (const float*)d_in[3];
    float* out = (float*)d_out;

    char* p = (char*)d_ws;
    u32* key  = (u32*)p; p += (size_t)BB * NN * 4;
    u32* bh   = (u32*)p; p += (size_t)BB * SB * NBINS * 4;   // suffix-hist slices
    u32* part = (u32*)p; p += (size_t)BB * RED * NBINS * 4;  // column-sum partials
    u32* cnt  = (u32*)p; p += 256;
    u64* cand = (u64*)p; p += (size_t)BB * CAP * 8;
    float* tks = (float*)p; p += (size_t)BB * K_PRE * 4;
    u32* meta = (u32*)p; p += (size_t)BB * K_PRE * 4;
    float* box7 = (float*)p; p += (size_t)BB * K_PRE * 7 * 4;
    float* cor  = (float*)p; p += (size_t)BB * K_PRE * 5 * 4;
    u64* maskT = (u64*)p; p += (size_t)BB * K_PRE * NW * 8;

    k_score_hist<<<BB * SB, 256, 0, stream>>>(cls, key, bh);
    k_red<<<BB * RED * 9, 64, 0, stream>>>(bh, part);
    k_scatterT<<<BB * SB, 256, 0, stream>>>(key, part, bh, cnt, cand);
    k_rankdec<<<BB * 16, 256, 0, stream>>>(cnt, cand, boxp, cls, dirp, anch, tks, meta, box7, cor);
    k_maskT<<<BB * 63, 256, 0, stream>>>(cor, maskT);
    k_nms_out<<<BB, 256, 0, stream>>>(meta, box7, tks, maskT, out);
}